// Round 7
// baseline (38.471 us; speedup 1.0000x reference)
//
#include <hip/hip_runtime.h>
#include <hip/hip_bf16.h>

// out = (Q K^T) V  ==  Q (K^T V)   [no softmax -> linear -> reassociate]
// B=2,H=8,S=4096,D=64 fp32. 16 head-slices of [4096,64].
//
// Z : zero the 16x64x64 fp32 accumulator M^T (64 KB)       [ws]
// K1: M^T[h][d][e] += chunk-partial V^T K via MFMA + fp32 atomicAdd
//     (LDS-staged global_load_lds x16B; frag cvt v_cvt_pk_bf16_f32)
// K3: out[i][d] = sum_e Q[i][e]*M[e][d]  via mfma_32x32x16_bf16,
//     B-frags cvt'd from fp32 M^T (L2-hot, 16 KB/head)
//
// Timing model (rounds 1-6): dur_us ~ 11 us harness overhead + warm kernels.

#define SD 262144  // S*D
#define SDIM 4096
#define DDIM 64
#define NH 16      // B*H
#define NCHUNK 64
#define CHUNK 64   // SDIM / NCHUNK

typedef short bf16x8 __attribute__((ext_vector_type(8)));
typedef float f32x16 __attribute__((ext_vector_type(16)));

union frag_cast { bf16x8 v; __hip_bfloat162 h[4]; };

// ---------------- Z: zero M accumulator (16 heads x 4096 fp32) ----------------
__global__ __launch_bounds__(256) void zero_m(float* __restrict__ m) {
    m[blockIdx.x * 256 + threadIdx.x] = 0.f;
}

// ---------------- K1: partial V^T K over a 64-row chunk (MFMA, LDS-staged) ----
// 4 waves/block; wave w owns quadrant (dh, eh) of the 64x64 partial M^T = V^T K.
//   A-frag: lane holds A[row=l31][k=kg+j] with A=V^T  -> ldsV[(s0+kg+j)*64 + dh+l31]
//   B-frag: lane holds B[k=kg+j][col=l31] with B=K    -> ldsK[(s0+kg+j)*64 + eh+l31]
//   D[row=d][col=e]: d=(r&3)+8*(r>>2)+4*(l>>5), e=l31
// Epilogue: fp32 atomicAdd into m32[h] (64 chunk-blocks accumulate per head).
__global__ __launch_bounds__(256) void ktv_mfma(const float* __restrict__ Kp,
                                                const float* __restrict__ Vp,
                                                float* __restrict__ m32) {
    __shared__ float ldsK[CHUNK * DDIM];   // 16 KB
    __shared__ float ldsV[CHUNK * DDIM];   // 16 KB

    const int g = blockIdx.x;      // [0, NH*NCHUNK)
    const int h = g >> 6;
    const int c = g & 63;
    const size_t base = (size_t)h * SD + (size_t)c * CHUNK * DDIM;

    const int w = threadIdx.x >> 6;
    const int l = threadIdx.x & 63;
    const int l31 = l & 31;
    const int kg = (l >> 5) * 8;
    const int dh = (w >> 1) * 32;
    const int eh = (w & 1) * 32;

    const float* Ksrc = Kp + base;
    const float* Vsrc = Vp + base;
#pragma unroll
    for (int i = 0; i < 4; ++i) {
        const int seg = w * 4 + i;          // 0..15, 256 floats each
        __builtin_amdgcn_global_load_lds(
            (const __attribute__((address_space(1))) void*)(Ksrc + seg * 256 + l * 4),
            (__attribute__((address_space(3))) void*)(ldsK + seg * 256),
            16, 0, 0);
        __builtin_amdgcn_global_load_lds(
            (const __attribute__((address_space(1))) void*)(Vsrc + seg * 256 + l * 4),
            (__attribute__((address_space(3))) void*)(ldsV + seg * 256),
            16, 0, 0);
    }
    __syncthreads();

    f32x16 acc = {};
#pragma unroll
    for (int s0 = 0; s0 < CHUNK; s0 += 16) {
        frag_cast ua, ub;
#pragma unroll
        for (int j = 0; j < 4; ++j) {
            const int r0 = (s0 + kg + 2 * j) * DDIM;
            const int r1 = (s0 + kg + 2 * j + 1) * DDIM;
            ua.h[j] = __float22bfloat162_rn(float2{ldsV[r0 + dh + l31],
                                                   ldsV[r1 + dh + l31]});
            ub.h[j] = __float22bfloat162_rn(float2{ldsK[r0 + eh + l31],
                                                   ldsK[r1 + eh + l31]});
        }
        acc = __builtin_amdgcn_mfma_f32_32x32x16_bf16(ua.v, ub.v, acc, 0, 0, 0);
    }

    float* mh = m32 + (size_t)h * 4096;
#pragma unroll
    for (int r = 0; r < 16; ++r) {
        const int d = (r & 3) + 8 * (r >> 2) + 4 * (l >> 5) + dh;
        atomicAdd(&mh[d * DDIM + eh + l31], acc[r]);
    }
}

// ---------------- K3: out = Q @ M via MFMA 32x32x16 bf16 ----------------
// 1024 blocks x 256 (16 waves/CU). Wave w owns 32 rows x 32 cols:
//   rows = qt*64 + (w>>1)*32, cols = (w&1)*32.
// A-frag: lane holds Q[row=l31][k=kg+j]  (fp32 -> cvt_pk bf16)
// B-frag: lane holds M[k=e][col=ch+l31] = m32[h][ch+l31][e], e=kk*16+kg+j
// C/D: col = ch+l31, row = (r&3) + 8*(r>>2) + 4*(l>>5)   [HW-verified r1-r6]
__global__ __launch_bounds__(256) void qm_gemm(const float* __restrict__ Qp,
                                               const float* __restrict__ m32,
                                               float* __restrict__ out) {
    const int bx = blockIdx.x;     // [0, NH*64)
    const int h = bx >> 6;
    const int qt = bx & 63;        // 64-row tile
    const int w = threadIdx.x >> 6;
    const int l = threadIdx.x & 63;
    const int l31 = l & 31;
    const int kg = (l >> 5) * 8;
    const int ch = (w & 1) * 32;   // column half
    const int rowbase = qt * 64 + (w >> 1) * 32;

    const float* Qh = Qp + (size_t)h * SD + (size_t)rowbase * DDIM;
    const float* Mh = m32 + (size_t)h * 4096;

    f32x16 acc = {};
#pragma unroll
    for (int kk = 0; kk < 4; ++kk) {
        // A: Q rows
        const float4* q4 = (const float4*)(Qh + (size_t)l31 * DDIM + kk * 16 + kg);
        const float4 q0 = q4[0], q1 = q4[1];
        frag_cast ua;
        ua.h[0] = __float22bfloat162_rn(float2{q0.x, q0.y});
        ua.h[1] = __float22bfloat162_rn(float2{q0.z, q0.w});
        ua.h[2] = __float22bfloat162_rn(float2{q1.x, q1.y});
        ua.h[3] = __float22bfloat162_rn(float2{q1.z, q1.w});
        // B: M^T row (d = ch+l31), 8 consecutive e
        const float4* m4 = (const float4*)(Mh + (size_t)(ch + l31) * DDIM + kk * 16 + kg);
        const float4 m0 = m4[0], m1 = m4[1];
        frag_cast ub;
        ub.h[0] = __float22bfloat162_rn(float2{m0.x, m0.y});
        ub.h[1] = __float22bfloat162_rn(float2{m0.z, m0.w});
        ub.h[2] = __float22bfloat162_rn(float2{m1.x, m1.y});
        ub.h[3] = __float22bfloat162_rn(float2{m1.z, m1.w});
        acc = __builtin_amdgcn_mfma_f32_32x32x16_bf16(ua.v, ub.v, acc, 0, 0, 0);
    }

    float* Oh = out + (size_t)h * SD + (size_t)rowbase * DDIM;
#pragma unroll
    for (int r = 0; r < 16; ++r) {
        const int row = (r & 3) + 8 * (r >> 2) + 4 * (l >> 5);
        Oh[(size_t)row * DDIM + ch + l31] = acc[r];
    }
}

extern "C" void kernel_launch(void* const* d_in, const int* in_sizes, int n_in,
                              void* d_out, int out_size, void* d_ws, size_t ws_size,
                              hipStream_t stream) {
    const float* q = (const float*)d_in[0];
    const float* k = (const float*)d_in[1];
    const float* v = (const float*)d_in[2];
    float* out = (float*)d_out;

    float* m32 = (float*)d_ws;     // 16 heads x 4096 fp32 = 64 KB

    zero_m<<<NH * 4096 / 256, 256, 0, stream>>>(m32);
    ktv_mfma<<<NH * NCHUNK, 256, 0, stream>>>(k, v, m32);
    qm_gemm<<<NH * 64, 256, 0, stream>>>(q, m32, out);
}

// Round 8
// 24.563 us; speedup vs baseline: 1.5662x; 1.5662x over previous
//
#include <hip/hip_runtime.h>
#include <hip/hip_bf16.h>

// out = (Q K^T) V  ==  Q (K^T V)   [no softmax -> linear -> reassociate]
// B=2,H=8,S=4096,D=64 fp32. 16 head-slices of [4096,64].
//
// K1: part[g][d][e] = sum_{s in 64-row chunk} V[s][d]*K[s][e]  via MFMA -> bf16
//     staging: per-lane contiguous float4 global loads -> regs -> ds_write_b128
//     (global_load_lds and scattered-dword staging both stuck at ~2.4 TB/s on
//      cold HBM; per-lane dwordx4 path measured at ~6.3 TB/s cold in K3)
// K2: Mt[h][d][e]   = sum_c part[h*64+c][d][e]  -> bf16          (128 KB)
// K3: out[i][d]     = sum_e Q[i][e]*M[e][d]  via mfma_32x32x16_bf16

#define SD 262144  // S*D
#define SDIM 4096
#define DDIM 64
#define NH 16      // B*H
#define NCHUNK 64
#define CHUNK 64   // SDIM / NCHUNK

typedef short bf16x8 __attribute__((ext_vector_type(8)));
typedef float f32x16 __attribute__((ext_vector_type(16)));

__device__ __forceinline__ unsigned short f2bf(float f) {
    unsigned int u = __float_as_uint(f);
    u += 0x7fffu + ((u >> 16) & 1u);   // round-to-nearest-even
    return (unsigned short)(u >> 16);
}

__device__ __forceinline__ float bf2f(unsigned short h) {
    return __uint_as_float((unsigned int)h << 16);
}

union frag_cast { bf16x8 v; __hip_bfloat162 h[4]; };

// ---------------- K1: partial V^T K over a 64-row chunk (MFMA, reg->LDS) ------
// 4 waves/block; wave w owns quadrant (dh, eh) of the 64x64 partial M^T = V^T K.
//   A-frag: lane holds A[row=l31][k=kg+j] with A=V^T  -> ldsV[(s0+kg+j)*64 + dh+l31]
//   B-frag: lane holds B[k=kg+j][col=l31] with B=K    -> ldsK[(s0+kg+j)*64 + eh+l31]
//   D[row=d][col=e]: d=(r&3)+8*(r>>2)+4*(l>>5), e=l31
__global__ __launch_bounds__(256) void ktv_mfma(const float* __restrict__ Kp,
                                                const float* __restrict__ Vp,
                                                unsigned short* __restrict__ part) {
    __shared__ float ldsK[CHUNK * DDIM];   // 16 KB
    __shared__ float ldsV[CHUNK * DDIM];   // 16 KB

    const int g = blockIdx.x;      // [0, NH*NCHUNK)
    const int h = g >> 6;
    const int c = g & 63;
    const size_t base = (size_t)h * SD + (size_t)c * CHUNK * DDIM;

    const int t = threadIdx.x;
    const int w = t >> 6;
    const int l = t & 63;
    const int l31 = l & 31;
    const int kg = (l >> 5) * 8;
    const int dh = (w >> 1) * 32;
    const int eh = (w & 1) * 32;

    // Stage: 8 fat per-lane loads (K3's proven cold-HBM pattern), then LDS.
    const float4* Ks4 = (const float4*)(Kp + base);
    const float4* Vs4 = (const float4*)(Vp + base);
    float4 kreg[4], vreg[4];
#pragma unroll
    for (int i = 0; i < 4; ++i) {
        kreg[i] = Ks4[i * 256 + t];
        vreg[i] = Vs4[i * 256 + t];
    }
#pragma unroll
    for (int i = 0; i < 4; ++i) {
        ((float4*)ldsK)[i * 256 + t] = kreg[i];
        ((float4*)ldsV)[i * 256 + t] = vreg[i];
    }
    __syncthreads();

    f32x16 acc = {};
#pragma unroll
    for (int s0 = 0; s0 < CHUNK; s0 += 16) {
        frag_cast ua, ub;
#pragma unroll
        for (int j = 0; j < 4; ++j) {
            const int r0 = (s0 + kg + 2 * j) * DDIM;
            const int r1 = (s0 + kg + 2 * j + 1) * DDIM;
            ua.h[j] = __float22bfloat162_rn(float2{ldsV[r0 + dh + l31],
                                                   ldsV[r1 + dh + l31]});
            ub.h[j] = __float22bfloat162_rn(float2{ldsK[r0 + eh + l31],
                                                   ldsK[r1 + eh + l31]});
        }
        acc = __builtin_amdgcn_mfma_f32_32x32x16_bf16(ua.v, ub.v, acc, 0, 0, 0);
    }

    unsigned short* pg = part + (size_t)g * 4096;
#pragma unroll
    for (int r = 0; r < 16; ++r) {
        const int d = (r & 3) + 8 * (r >> 2) + 4 * (l >> 5) + dh;
        pg[(size_t)d * DDIM + eh + l31] = f2bf(acc[r]);
    }
}

// ---------------- K2: reduce 64 bf16 partials -> Mt bf16 [h][d][e] ----------------
__global__ __launch_bounds__(256) void reduce_mt(const unsigned short* __restrict__ part,
                                                 unsigned short* __restrict__ mt) {
    const int b = blockIdx.x;      // [0,256)
    const int h = b >> 4;
    const int d = (b & 15) * 4 + (threadIdx.x >> 6);
    const int e = threadIdx.x & 63;
    const unsigned short* ph = part + (size_t)h * NCHUNK * 4096 + d * 64 + e;
    float s = 0.f;
#pragma unroll
    for (int c = 0; c < NCHUNK; ++c) s += bf2f(ph[(size_t)c * 4096]);
    mt[(size_t)h * 4096 + d * 64 + e] = f2bf(s);
}

// ---------------- K3: out = Q @ M via MFMA 32x32x16 bf16 ----------------
// A-frag: lane holds Q[row=l&31][k=(l>>5)*8+j]; B-frag: lane holds Mt[d][e] rows.
// C/D: col = l&31, row = (r&3) + 8*(r>>2) + 4*(l>>5)
__global__ __launch_bounds__(256) void qm_gemm(const float* __restrict__ Qp,
                                               const unsigned short* __restrict__ mt,
                                               float* __restrict__ out) {
    const int bx = blockIdx.x;     // [0, NH*32)
    const int h = bx >> 5;
    const int qt = bx & 31;        // 128-row tile
    const int w = threadIdx.x >> 6;
    const int l = threadIdx.x & 63;
    const int l31 = l & 31;
    const int kg = (l >> 5) * 8;

    const float* Qh = Qp + (size_t)h * SD + (size_t)(qt * 128 + w * 32) * DDIM;
    const unsigned short* Mh = mt + (size_t)h * 4096;

    bf16x8 a[4];
#pragma unroll
    for (int kk = 0; kk < 4; ++kk) {
        const float4* q4 = (const float4*)(Qh + (size_t)l31 * DDIM + kk * 16 + kg);
        const float4 q0 = q4[0], q1 = q4[1];
        frag_cast u;
        u.h[0] = __float22bfloat162_rn(float2{q0.x, q0.y});
        u.h[1] = __float22bfloat162_rn(float2{q0.z, q0.w});
        u.h[2] = __float22bfloat162_rn(float2{q1.x, q1.y});
        u.h[3] = __float22bfloat162_rn(float2{q1.z, q1.w});
        a[kk] = u.v;
    }

    f32x16 acc0 = {};
    f32x16 acc1 = {};
#pragma unroll
    for (int kk = 0; kk < 4; ++kk) {
        const bf16x8 b0 = *(const bf16x8*)(Mh + (size_t)l31 * 64 + kk * 16 + kg);
        const bf16x8 b1 = *(const bf16x8*)(Mh + (size_t)(l31 + 32) * 64 + kk * 16 + kg);
        acc0 = __builtin_amdgcn_mfma_f32_32x32x16_bf16(a[kk], b0, acc0, 0, 0, 0);
        acc1 = __builtin_amdgcn_mfma_f32_32x32x16_bf16(a[kk], b1, acc1, 0, 0, 0);
    }

    float* Oh = out + (size_t)h * SD + (size_t)(qt * 128 + w * 32) * DDIM;
#pragma unroll
    for (int r = 0; r < 16; ++r) {
        const int row = (r & 3) + 8 * (r >> 2) + 4 * (l >> 5);
        Oh[(size_t)row * DDIM + l31] = acc0[r];
        Oh[(size_t)row * DDIM + 32 + l31] = acc1[r];
    }
}

extern "C" void kernel_launch(void* const* d_in, const int* in_sizes, int n_in,
                              void* d_out, int out_size, void* d_ws, size_t ws_size,
                              hipStream_t stream) {
    const float* q = (const float*)d_in[0];
    const float* k = (const float*)d_in[1];
    const float* v = (const float*)d_in[2];
    float* out = (float*)d_out;

    unsigned short* part = (unsigned short*)d_ws;                     // 8.4 MB bf16
    unsigned short* mt =
        (unsigned short*)((char*)d_ws + (size_t)NH * NCHUNK * 4096 * 2);  // 128 KB

    ktv_mfma<<<NH * NCHUNK, 256, 0, stream>>>(k, v, part);
    reduce_mt<<<256, 256, 0, stream>>>(part, mt);
    qm_gemm<<<NH * 32, 256, 0, stream>>>(q, mt, out);
}

// Round 9
// 22.568 us; speedup vs baseline: 1.7047x; 1.0884x over previous
//
#include <hip/hip_runtime.h>
#include <hip/hip_bf16.h>

// out = (Q K^T) V  ==  Q (K^T V)   [no softmax -> linear -> reassociate]
// B=2,H=8,S=4096,D=64 fp32. 16 head-slices of [4096,64].
//
// Timing model (rounds 1-8): dur ~ 11us fixed + sum(kernel traffic / 6.3TB/s).
// Compulsory traffic 67.2 MB => floor ~21.7us. This round halves the `part`
// round-trip (NCHUNK 64->32): 24.5 -> ~23.
//
// K1: part[g][d][e] = sum_{s in 128-row chunk} V[s][d]*K[s][e] via MFMA -> bf16
//     staging: per-lane contiguous float4 -> regs -> ds_write_b128
// K2: Mt[h][d][e]   = sum_c part[h*32+c][d][e]  -> bf16
// K3: out[i][d]     = sum_e Q[i][e]*M[e][d]  via mfma_32x32x16_bf16

#define SD 262144  // S*D
#define SDIM 4096
#define DDIM 64
#define NH 16      // B*H
#define NCHUNK 32
#define CHUNK 128  // SDIM / NCHUNK

typedef short bf16x8 __attribute__((ext_vector_type(8)));
typedef float f32x16 __attribute__((ext_vector_type(16)));

__device__ __forceinline__ unsigned short f2bf(float f) {
    unsigned int u = __float_as_uint(f);
    u += 0x7fffu + ((u >> 16) & 1u);   // round-to-nearest-even
    return (unsigned short)(u >> 16);
}

__device__ __forceinline__ float bf2f(unsigned short h) {
    return __uint_as_float((unsigned int)h << 16);
}

union frag_cast { bf16x8 v; __hip_bfloat162 h[4]; };

// ---------------- K1: partial V^T K over a 128-row chunk (MFMA, reg->LDS) -----
// 4 waves/block; wave w owns quadrant (dh, eh) of the 64x64 partial M^T = V^T K.
//   A-frag: lane holds A[row=l31][k=kg+j] with A=V^T  -> ldsV[(s0+kg+j)*64 + dh+l31]
//   B-frag: lane holds B[k=kg+j][col=l31] with B=K    -> ldsK[(s0+kg+j)*64 + eh+l31]
//   D[row=d][col=e]: d=(r&3)+8*(r>>2)+4*(l>>5), e=l31
__global__ __launch_bounds__(256) void ktv_mfma(const float* __restrict__ Kp,
                                                const float* __restrict__ Vp,
                                                unsigned short* __restrict__ part) {
    __shared__ float ldsK[CHUNK * DDIM];   // 32 KB
    __shared__ float ldsV[CHUNK * DDIM];   // 32 KB

    const int g = blockIdx.x;      // [0, NH*NCHUNK) = [0,512)
    const int h = g >> 5;
    const int c = g & 31;
    const size_t base = (size_t)h * SD + (size_t)c * CHUNK * DDIM;

    const int t = threadIdx.x;
    const int w = t >> 6;
    const int l = t & 63;
    const int l31 = l & 31;
    const int kg = (l >> 5) * 8;
    const int dh = (w >> 1) * 32;
    const int eh = (w & 1) * 32;

    // Stage: 16 fat per-lane dwordx4 loads -> regs -> LDS (proven 6.3 TB/s cold).
    const float4* Ks4 = (const float4*)(Kp + base);
    const float4* Vs4 = (const float4*)(Vp + base);
    float4 kreg[8], vreg[8];
#pragma unroll
    for (int i = 0; i < 8; ++i) {
        kreg[i] = Ks4[i * 256 + t];
        vreg[i] = Vs4[i * 256 + t];
    }
#pragma unroll
    for (int i = 0; i < 8; ++i) {
        ((float4*)ldsK)[i * 256 + t] = kreg[i];
        ((float4*)ldsV)[i * 256 + t] = vreg[i];
    }
    __syncthreads();

    f32x16 acc = {};
#pragma unroll
    for (int s0 = 0; s0 < CHUNK; s0 += 16) {
        frag_cast ua, ub;
#pragma unroll
        for (int j = 0; j < 4; ++j) {
            const int r0 = (s0 + kg + 2 * j) * DDIM;
            const int r1 = (s0 + kg + 2 * j + 1) * DDIM;
            ua.h[j] = __float22bfloat162_rn(float2{ldsV[r0 + dh + l31],
                                                   ldsV[r1 + dh + l31]});
            ub.h[j] = __float22bfloat162_rn(float2{ldsK[r0 + eh + l31],
                                                   ldsK[r1 + eh + l31]});
        }
        acc = __builtin_amdgcn_mfma_f32_32x32x16_bf16(ua.v, ub.v, acc, 0, 0, 0);
    }

    unsigned short* pg = part + (size_t)g * 4096;
#pragma unroll
    for (int r = 0; r < 16; ++r) {
        const int d = (r & 3) + 8 * (r >> 2) + 4 * (l >> 5) + dh;
        pg[(size_t)d * DDIM + eh + l31] = f2bf(acc[r]);
    }
}

// ---------------- K2: reduce 32 bf16 partials -> Mt bf16 [h][d][e] ----------------
__global__ __launch_bounds__(256) void reduce_mt(const unsigned short* __restrict__ part,
                                                 unsigned short* __restrict__ mt) {
    const int b = blockIdx.x;      // [0,256)
    const int h = b >> 4;
    const int d = (b & 15) * 4 + (threadIdx.x >> 6);
    const int e = threadIdx.x & 63;
    const unsigned short* ph = part + (size_t)h * NCHUNK * 4096 + d * 64 + e;
    float s = 0.f;
#pragma unroll
    for (int c = 0; c < NCHUNK; ++c) s += bf2f(ph[(size_t)c * 4096]);
    mt[(size_t)h * 4096 + d * 64 + e] = f2bf(s);
}

// ---------------- K3: out = Q @ M via MFMA 32x32x16 bf16 ----------------
// A-frag: lane holds Q[row=l&31][k=(l>>5)*8+j]; B-frag: lane holds Mt[d][e] rows.
// C/D: col = l&31, row = (r&3) + 8*(r>>2) + 4*(l>>5)
__global__ __launch_bounds__(256) void qm_gemm(const float* __restrict__ Qp,
                                               const unsigned short* __restrict__ mt,
                                               float* __restrict__ out) {
    const int bx = blockIdx.x;     // [0, NH*32)
    const int h = bx >> 5;
    const int qt = bx & 31;        // 128-row tile
    const int w = threadIdx.x >> 6;
    const int l = threadIdx.x & 63;
    const int l31 = l & 31;
    const int kg = (l >> 5) * 8;

    const float* Qh = Qp + (size_t)h * SD + (size_t)(qt * 128 + w * 32) * DDIM;
    const unsigned short* Mh = mt + (size_t)h * 4096;

    bf16x8 a[4];
#pragma unroll
    for (int kk = 0; kk < 4; ++kk) {
        const float4* q4 = (const float4*)(Qh + (size_t)l31 * DDIM + kk * 16 + kg);
        const float4 q0 = q4[0], q1 = q4[1];
        frag_cast u;
        u.h[0] = __float22bfloat162_rn(float2{q0.x, q0.y});
        u.h[1] = __float22bfloat162_rn(float2{q0.z, q0.w});
        u.h[2] = __float22bfloat162_rn(float2{q1.x, q1.y});
        u.h[3] = __float22bfloat162_rn(float2{q1.z, q1.w});
        a[kk] = u.v;
    }

    f32x16 acc0 = {};
    f32x16 acc1 = {};
#pragma unroll
    for (int kk = 0; kk < 4; ++kk) {
        const bf16x8 b0 = *(const bf16x8*)(Mh + (size_t)l31 * 64 + kk * 16 + kg);
        const bf16x8 b1 = *(const bf16x8*)(Mh + (size_t)(l31 + 32) * 64 + kk * 16 + kg);
        acc0 = __builtin_amdgcn_mfma_f32_32x32x16_bf16(a[kk], b0, acc0, 0, 0, 0);
        acc1 = __builtin_amdgcn_mfma_f32_32x32x16_bf16(a[kk], b1, acc1, 0, 0, 0);
    }

    float* Oh = out + (size_t)h * SD + (size_t)(qt * 128 + w * 32) * DDIM;
#pragma unroll
    for (int r = 0; r < 16; ++r) {
        const int row = (r & 3) + 8 * (r >> 2) + 4 * (l >> 5);
        Oh[(size_t)row * DDIM + l31] = acc0[r];
        Oh[(size_t)row * DDIM + 32 + l31] = acc1[r];
    }
}

extern "C" void kernel_launch(void* const* d_in, const int* in_sizes, int n_in,
                              void* d_out, int out_size, void* d_ws, size_t ws_size,
                              hipStream_t stream) {
    const float* q = (const float*)d_in[0];
    const float* k = (const float*)d_in[1];
    const float* v = (const float*)d_in[2];
    float* out = (float*)d_out;

    unsigned short* part = (unsigned short*)d_ws;                     // 4.2 MB bf16
    unsigned short* mt =
        (unsigned short*)((char*)d_ws + (size_t)NH * NCHUNK * 4096 * 2);  // 128 KB

    ktv_mfma<<<NH * NCHUNK, 256, 0, stream>>>(k, v, part);
    reduce_mt<<<256, 256, 0, stream>>>(part, mt);
    qm_gemm<<<NH * 32, 256, 0, stream>>>(q, mt, out);
}